// Round 5
// baseline (167.948 us; speedup 1.0000x reference)
//
#include <hip/hip_runtime.h>

// Problem constants
#define NPIX   32768      // B*H*W
#define NEMB_  8192
#define EMB_   64
#define CH_    128
#define CAPP   768        // LDS pair-queue capacity

// d_out layout (float elements)
#define OUT_OFF  0
#define ZQ_OFF   2097152
#define LOSS_OFF 4194304
#define IND_OFF  4194305

typedef _Float16 h8   __attribute__((ext_vector_type(8)));
typedef float    f16f __attribute__((ext_vector_type(16)));

// ---------------------------------------------------------------------------
// ordered-float key: lexicographic (dist, index) min == np argmin semantics
__device__ __forceinline__ unsigned long long pack_key(float d, int m)
{
    unsigned fb = __float_as_uint(d);
    fb ^= ((int)fb < 0) ? 0xFFFFFFFFu : 0x80000000u;
    return ((unsigned long long)fb << 32) | (unsigned)m;
}

// ---------------------------------------------------------------------------
// Single fused kernel. grid 256 x 1024 threads (16 waves, 4 waves/SIMD),
// 128 px/block. Phases:
//   A: block b packs codebook tile b (wave 0 only) -> fence -> wdone++
//   B: 1x1-conv projection into LDS (c-blocked pw s_load_dwordx4, f32,
//      FMA order bit-identical to previous rounds)
//   C: bfr fragments from LDS
//   D: spin until all 256 tiles packed (already done by now) + acquire
//   E: MFMA scan, 2-tile-deep A prefetch, top-3 per (px,chunk)
//   F: certify -> pair queue -> f32 drain -> winners -> outputs -> loss
// Deadlock-safe: 256 blocks <= 256 CUs at this occupancy => all resident.
__global__ __launch_bounds__(1024, 4) void k_vq(
    const float* __restrict__ z,  const float* __restrict__ pw,
    const float* __restrict__ pb, const float* __restrict__ ew,
    float4* __restrict__ W4, float* __restrict__ wsq, float* __restrict__ wsqp,
    float* __restrict__ out, float* __restrict__ lacc, int* __restrict__ done,
    int* __restrict__ wdone)
{
    __shared__ __align__(16) float xs[128][68];        // z_e rows, later winners
    __shared__ float s1s[1024], s2s[1024], s3s[1024];  // [px][ch], ch=0..7
    __shared__ short i1s[1024], i2s[1024];
    __shared__ float xsqp_s[8][128];
    __shared__ float thr_s[128];
    __shared__ int   pairs[CAPP];
    __shared__ unsigned long long pbest[128];
    __shared__ int   winner_s[128];
    __shared__ int   smask[128];
    __shared__ float wred[16];
    __shared__ int   npair_s;
    __shared__ float wm_s;

    const int tid  = threadIdx.x;
    const int wv   = tid >> 6;                       // 0..15
    const int lane = tid & 63;
    const int n0   = blockIdx.x * 128;
    const int hlf  = lane >> 5;

    if (tid == 0) npair_s = 0;
    if (tid < 128) { smask[tid] = 0; pbest[tid] = ~0ULL; }

    // ---- Phase A: pack codebook tile blockIdx.x (wave 0, lanes 0..31) ----
    if (wv == 0) {
        if (lane < 32) {
            const int m = blockIdx.x * 32 + lane;
            const float4* wr = (const float4*)(ew + (size_t)m * EMB_);
            float w[EMB_];
            float s = 0.f;
            #pragma unroll
            for (int i = 0; i < 16; i++) {
                float4 v = wr[i];
                w[4*i] = v.x; w[4*i+1] = v.y; w[4*i+2] = v.z; w[4*i+3] = v.w;
                s += v.x*v.x + v.y*v.y + v.z*v.z + v.w*v.w;
            }
            wsq[m] = s;
            float sh = (float)(_Float16)s;
            float sl = s - sh;
            const int t  = blockIdx.x;
            const int li = lane;
            #pragma unroll
            for (int s5 = 0; s5 < 4; s5++) {
                #pragma unroll
                for (int h = 0; h < 2; h++) {
                    h8 hh;
                    #pragma unroll
                    for (int j = 0; j < 8; j++) hh[j] = (_Float16)w[s5*16 + h*8 + j];
                    W4[(size_t)(t * 5 + s5) * 64 + h * 32 + li] = __builtin_bit_cast(float4, hh);
                }
            }
            {
                h8 hh;
                #pragma unroll
                for (int j = 0; j < 8; j++) hh[j] = (_Float16)0.f;
                hh[0] = (_Float16)sh; hh[1] = (_Float16)sl;
                W4[(size_t)(t * 5 + 4) * 64 + 0 * 32 + li] = __builtin_bit_cast(float4, hh);
                #pragma unroll
                for (int j = 0; j < 8; j++) hh[j] = (_Float16)0.f;
                W4[(size_t)(t * 5 + 4) * 64 + 1 * 32 + li] = __builtin_bit_cast(float4, hh);
            }
            float sm = s;
            #pragma unroll
            for (int o = 16; o > 0; o >>= 1) sm = fmaxf(sm, __shfl_xor(sm, o));
            if (lane == 0) wsqp[blockIdx.x] = sm;
        }
        __threadfence();                 // drain this wave's stores (release)
        if (tid == 0) atomicAdd(wdone, 1);
    }

    // ---- Phase B: fused projection (oct = tid>>7 wave-uniform) ----
    // c-blocked: per 4 channels, 8x s_load_dwordx4 of pw rows (contiguous),
    // FMA order per accumulator is strictly c-ascending (bit-identical).
    {
        const int oct = tid >> 7;
        const int pxp = tid & 127;
        const int e0  = __builtin_amdgcn_readfirstlane(oct << 3);  // SGPR
        const float* pwb = pw + e0 * CH_;                 // rows e0..e0+7
        const float* zp = z + (size_t)(n0 >> 10) * (CH_ * 1024) + (n0 & 1023) + pxp;
        float acc[8];
        #pragma unroll
        for (int j = 0; j < 8; j++) acc[j] = 0.f;
        #pragma unroll 2
        for (int c = 0; c < CH_; c += 4) {
            const float zv0 = zp[(size_t)(c + 0) * 1024];   // coalesced
            const float zv1 = zp[(size_t)(c + 1) * 1024];
            const float zv2 = zp[(size_t)(c + 2) * 1024];
            const float zv3 = zp[(size_t)(c + 3) * 1024];
            #pragma unroll
            for (int j = 0; j < 8; j++) {
                const float4 w = *(const float4*)(pwb + j * CH_ + c);  // s_load_dwordx4
                acc[j] = fmaf(zv3, w.w, fmaf(zv2, w.z,
                         fmaf(zv1, w.y, fmaf(zv0, w.x, acc[j]))));
            }
        }
        const float4* pb4 = (const float4*)(pb + e0);
        float4 b0 = pb4[0], b1 = pb4[1];
        acc[0] += b0.x; acc[1] += b0.y; acc[2] += b0.z; acc[3] += b0.w;
        acc[4] += b1.x; acc[5] += b1.y; acc[6] += b1.z; acc[7] += b1.w;
        float sq = 0.f;
        #pragma unroll
        for (int j = 0; j < 8; j++) sq += acc[j] * acc[j];
        ((float4*)&xs[pxp][0])[oct * 2]     = make_float4(acc[0], acc[1], acc[2], acc[3]);
        ((float4*)&xs[pxp][0])[oct * 2 + 1] = make_float4(acc[4], acc[5], acc[6], acc[7]);
        xsqp_s[oct][pxp] = sq;
    }
    __syncthreads();

    const int ch = wv & 7;                 // chunk: tiles ch*32 .. ch*32+31
    const int pg = wv >> 3;                // px-group: px pg*64 .. pg*64+63

    // ---- Phase C: B-fragments from LDS (2 px-tiles x 4 K-steps + tail) ----
    h8 bfr[2][4];
    #pragma unroll
    for (int j = 0; j < 2; j++) {
        const int px = pg * 64 + j * 32 + (lane & 31);
        #pragma unroll
        for (int s5 = 0; s5 < 4; s5++) {
            float4 u0 = *(const float4*)(&xs[px][s5 * 16 + hlf * 8]);
            float4 u1 = *(const float4*)(&xs[px][s5 * 16 + hlf * 8 + 4]);
            h8 hh;
            hh[0]=(_Float16)u0.x; hh[1]=(_Float16)u0.y; hh[2]=(_Float16)u0.z; hh[3]=(_Float16)u0.w;
            hh[4]=(_Float16)u1.x; hh[5]=(_Float16)u1.y; hh[6]=(_Float16)u1.z; hh[7]=(_Float16)u1.w;
            bfr[j][s5] = hh;
        }
    }
    h8 btail;                              // px-independent tail fragment
    {
        h8 hh;
        #pragma unroll
        for (int q = 0; q < 8; q++) hh[q] = (_Float16)0.f;
        if (hlf == 0) { hh[0] = (_Float16)-0.5f; hh[1] = (_Float16)-0.5f; }
        btail = hh;
    }

    // ---- Phase D: wait for all tiles packed (usually already true) ----
    if (tid == 0) {
        while (atomicAdd(wdone, 0) < 256) { }
        __threadfence();                   // acquire
    }
    __syncthreads();
    if (tid < 64) {
        float w = fmaxf(fmaxf(wsqp[tid], wsqp[tid + 64]),
                        fmaxf(wsqp[tid + 128], wsqp[tid + 192]));
        #pragma unroll
        for (int o = 32; o > 0; o >>= 1) w = fmaxf(w, __shfl_xor(w, o));
        if (tid == 0) wm_s = w;
    }

    // ---- Phase E: coarse MFMA scan, 2-tile-deep A prefetch ----
    const f16f kzero = {0,0,0,0,0,0,0,0,0,0,0,0,0,0,0,0};
    float s1[2], s2[2], s3[2];
    int   i1[2], i2[2];
    #pragma unroll
    for (int j = 0; j < 2; j++) { s1[j]=s2[j]=s3[j]=-3.0e38f; i1[j]=i2[j]=0; }

    const int tb = ch * 32;
    const float4* Wb = W4 + (size_t)tb * 320 + lane;
    float4 A0[5], A1[5];
    #pragma unroll
    for (int s = 0; s < 5; s++) A0[s] = Wb[s * 64];
    #pragma unroll
    for (int s = 0; s < 5; s++) A1[s] = Wb[320 + s * 64];

#define REDUCE_J(ACC, JJ, GT)                                                  \
    {                                                                          \
        float t0 = fmaxf(fmaxf(ACC[0],  ACC[1]),  ACC[2]);                     \
        float t1 = fmaxf(fmaxf(ACC[3],  ACC[4]),  ACC[5]);                     \
        float t2 = fmaxf(fmaxf(ACC[6],  ACC[7]),  ACC[8]);                     \
        float t3 = fmaxf(fmaxf(ACC[9],  ACC[10]), ACC[11]);                    \
        float t4 = fmaxf(fmaxf(ACC[12], ACC[13]), ACC[14]);                    \
        float v  = fmaxf(fmaxf(fmaxf(t0, t1), fmaxf(t2, t3)),                  \
                         fmaxf(t4, ACC[15]));                                  \
        v = fmaxf(v, __shfl_xor(v, 32));                                       \
        bool c1 = v > s1[JJ];                                                  \
        bool c2 = v > s2[JJ];                                                  \
        int  cand = c1 ? i1[JJ] : (GT);                                        \
        i2[JJ] = c2 ? cand : i2[JJ];                                           \
        s3[JJ] = fmaxf(fminf(s2[JJ], v), s3[JJ]);                              \
        s3[JJ] = fminf(s3[JJ], fmaxf(s2[JJ], v));                              \
        s2[JJ] = fmaxf(fminf(s1[JJ], v), fminf(s2[JJ], fmaxf(s1[JJ], v)));     \
        i1[JJ] = c1 ? (GT) : i1[JJ];                                           \
        s1[JJ] = fmaxf(s1[JJ], v);                                             \
    }

#define TILE_BODY(AB, TT, PF)                                                  \
    {                                                                          \
        const int gt = tb + (TT);                                              \
        f16f acc0 = __builtin_amdgcn_mfma_f32_32x32x16_f16(                    \
            __builtin_bit_cast(h8, AB[0]), bfr[0][0], kzero, 0, 0, 0);         \
        _Pragma("unroll")                                                      \
        for (int s = 1; s < 4; s++)                                            \
            acc0 = __builtin_amdgcn_mfma_f32_32x32x16_f16(                     \
                __builtin_bit_cast(h8, AB[s]), bfr[0][s], acc0, 0, 0, 0);      \
        acc0 = __builtin_amdgcn_mfma_f32_32x32x16_f16(                         \
            __builtin_bit_cast(h8, AB[4]), btail, acc0, 0, 0, 0);              \
        REDUCE_J(acc0, 0, gt)                                                  \
        f16f acc1 = __builtin_amdgcn_mfma_f32_32x32x16_f16(                    \
            __builtin_bit_cast(h8, AB[0]), bfr[1][0], kzero, 0, 0, 0);         \
        _Pragma("unroll")                                                      \
        for (int s = 1; s < 4; s++)                                            \
            acc1 = __builtin_amdgcn_mfma_f32_32x32x16_f16(                     \
                __builtin_bit_cast(h8, AB[s]), bfr[1][s], acc1, 0, 0, 0);      \
        acc1 = __builtin_amdgcn_mfma_f32_32x32x16_f16(                         \
            __builtin_bit_cast(h8, AB[4]), btail, acc1, 0, 0, 0);              \
        {                                                                      \
            const int tp = (PF) < 32 ? (PF) : 30;                              \
            const float4* wp = Wb + (size_t)tp * 320;                          \
            _Pragma("unroll")                                                  \
            for (int s = 0; s < 5; s++) AB[s] = wp[s * 64];                    \
        }                                                                      \
        REDUCE_J(acc1, 1, gt)                                                  \
    }

    for (int tt = 0; tt < 32; tt += 2) {
        TILE_BODY(A0, tt,     tt + 2)
        TILE_BODY(A1, tt + 1, tt + 3)
    }
#undef TILE_BODY
#undef REDUCE_J

    if (lane < 32) {
        #pragma unroll
        for (int j = 0; j < 2; j++) {
            const int px = pg * 64 + j * 32 + lane;
            const int cell = px * 8 + ch;
            s1s[cell] = s1[j]; s2s[cell] = s2[j]; s3s[cell] = s3[j];
            i1s[cell] = (short)i1[j]; i2s[cell] = (short)i2[j];
        }
    }
    __syncthreads();

    // ---- certify ----
    if (tid < 128) {
        float s1g = s1s[tid * 8];
        #pragma unroll
        for (int c = 1; c < 8; c++) s1g = fmaxf(s1g, s1s[tid * 8 + c]);
        float xq = xsqp_s[0][tid];
        #pragma unroll
        for (int o = 1; o < 8; o++) xq += xsqp_s[o][tid];
        float E = 0.00125f * sqrtf(xq * wm_s) + 1e-5f * wm_s + 3e-4f;
        thr_s[tid] = s1g - 2.0f * E;
    }
    __syncthreads();
    // ---- push candidate (px, tile) pairs (global tile ids 0..255) ----
    {
        const int cell = tid;                        // 128 px x 8 ch
        const int px = cell >> 3, chh = cell & 7;
        const float th = thr_s[px];
        const float cs1 = s1s[cell], cs2 = s2s[cell], cs3 = s3s[cell];
        if (cs3 >= th) {
            int pos = atomicAdd(&npair_s, 32);
            if (pos + 32 <= CAPP) {
                for (int t = 0; t < 32; t++)
                    pairs[pos + t] = (px << 8) | (chh * 32 + t);
            } else {
                for (int t = 0; t < 32; t++)
                    if (pos + t < CAPP) pairs[pos + t] = -1;
                smask[px] = 1;
            }
        } else {
            if (cs1 >= th) {
                int pos = atomicAdd(&npair_s, 1);
                if (pos < CAPP) pairs[pos] = (px << 8) | (int)i1s[cell];
                else smask[px] = 1;
            }
            if (cs2 >= th) {
                int pos = atomicAdd(&npair_s, 1);
                if (pos < CAPP) pairs[pos] = (px << 8) | (int)i2s[cell];
                else smask[px] = 1;
            }
        }
    }
    __syncthreads();
    const int np = npair_s < CAPP ? npair_s : CAPP;

    // ---- coalesced drain: one tile per wave-iter; 8 x 1KB contiguous ----
    const int lg = lane >> 4;
    const int ld = lane & 15;
    for (int i = wv; i < np; i += 16) {
        const int pr = pairs[i];
        if (pr < 0) continue;
        const int p = pr >> 8;
        if (smask[p]) continue;
        const int t = pr & 255;
        const float4* tb4 = (const float4*)(ew + (size_t)t * 2048);
        float4 wq[8];
        #pragma unroll
        for (int q = 0; q < 8; q++) wq[q] = tb4[q * 64 + lane];
        const float4 xq = *(const float4*)(&xs[p][ld * 4]);
        unsigned long long best = ~0ULL;
        #pragma unroll
        for (int q = 0; q < 8; q++) {
            float dp = wq[q].x*xq.x + wq[q].y*xq.y + wq[q].z*xq.z + wq[q].w*xq.w;
            dp += __shfl_xor(dp, 1);
            dp += __shfl_xor(dp, 2);
            dp += __shfl_xor(dp, 4);
            dp += __shfl_xor(dp, 8);
            const int m = t * 32 + q * 4 + lg;
            unsigned long long key = pack_key(fmaf(-2.f, dp, wsq[m]), m);
            best = key < best ? key : best;
        }
        { unsigned long long o = __shfl_xor(best, 16); best = o < best ? o : best; }
        { unsigned long long o = __shfl_xor(best, 32); best = o < best ? o : best; }
        if (lane == 0) atomicMin(&pbest[p], best);
    }
    // ---- overflow fallback: full codebook rescan (statistically never) ----
    for (int p = wv; p < 128; p += 16) {
        if (!smask[p]) continue;
        const float4 xq = *(const float4*)(&xs[p][ld * 4]);
        unsigned long long bk = ~0ULL;
        for (int t = 0; t < 256; t++) {
            const float4* tb4 = (const float4*)(ew + (size_t)t * 2048);
            #pragma unroll
            for (int q = 0; q < 8; q++) {
                float4 wv4 = tb4[q * 64 + lane];
                float dp = wv4.x*xq.x + wv4.y*xq.y + wv4.z*xq.z + wv4.w*xq.w;
                dp += __shfl_xor(dp, 1);
                dp += __shfl_xor(dp, 2);
                dp += __shfl_xor(dp, 4);
                dp += __shfl_xor(dp, 8);
                const int m = t * 32 + q * 4 + lg;
                unsigned long long key = pack_key(fmaf(-2.f, dp, wsq[m]), m);
                bk = key < bk ? key : bk;
            }
        }
        { unsigned long long o = __shfl_xor(bk, 16); bk = o < bk ? o : bk; }
        { unsigned long long o = __shfl_xor(bk, 32); bk = o < bk ? o : bk; }
        if (lane == 0) atomicMin(&pbest[p], bk);
    }
    __syncthreads();
    if (tid < 128) {
        const int win = (int)(unsigned)(pbest[tid] & 0xFFFFFFFFULL);
        winner_s[tid] = win;
        out[IND_OFF + n0 + tid] = (float)win;
    }
    __syncthreads();
    // ---- gather winner rows (8 thr/px), z_q writes, loss partials ----
    float lsum = 0.f;
    {
        const int px = tid >> 3, sg = tid & 7;
        const int win = winner_s[px];
        const float4* wr = (const float4*)(ew + (size_t)win * EMB_ + sg * 8);
        float4* xr  = (float4*)(&xs[px][sg * 8]);
        float4* zq4 = (float4*)(out + ZQ_OFF + (size_t)(n0 + px) * EMB_ + sg * 8);
        #pragma unroll
        for (int i = 0; i < 2; i++) {
            float4 w4v = wr[i];
            float4 z4  = xr[i];
            float d0 = w4v.x - z4.x, d1 = w4v.y - z4.y;
            float d2 = w4v.z - z4.z, d3 = w4v.w - z4.w;
            lsum += d0*d0 + d1*d1 + d2*d2 + d3*d3;
            xr[i]  = w4v;
            zq4[i] = w4v;
        }
    }
    __syncthreads();
    // ---- transposed out writes (64e x 128px, 512-B runs) ----
    {
        const int bI  = n0 >> 10;
        const int hw0 = n0 & 1023;
        float* ob = out + OUT_OFF + (size_t)bI * (EMB_ * 1024) + hw0;
        #pragma unroll
        for (int r = 0; r < 8; r++) {
            const int idx = r * 1024 + tid;
            const int e = idx >> 7, px = idx & 127;
            ob[(size_t)e * 1024 + px] = xs[px][e];
        }
    }
    // ---- loss reduction + final scalar ----
    {
        float v = lsum;
        #pragma unroll
        for (int o = 1; o < 64; o <<= 1) v += __shfl_xor(v, o);
        if (lane == 0) wred[wv] = v;
    }
    __syncthreads();
    if (tid == 0) {
        float s = wred[0];
        #pragma unroll
        for (int k = 1; k < 16; k++) s += wred[k];
        atomicAdd(lacc, s);
        __threadfence();
        int old = atomicAdd(done, 1);
        if (old == (int)gridDim.x - 1) {
            float tot = atomicAdd(lacc, 0.0f);
            out[LOSS_OFF] = 12.5f * (tot / 2097152.0f);
        }
    }
}

// ---------------------------------------------------------------------------
extern "C" void kernel_launch(void* const* d_in, const int* in_sizes, int n_in,
                              void* d_out, int out_size, void* d_ws, size_t ws_size,
                              hipStream_t stream)
{
    const float* z  = (const float*)d_in[0];
    const float* pw = (const float*)d_in[1];
    const float* pb = (const float*)d_in[2];
    const float* ew = (const float*)d_in[3];
    float* out = (float*)d_out;

    char* ws = (char*)d_ws;
    float4* W4   = (float4*)(ws);                      // 1,310,720
    float*  wsq  = (float*) (ws + 1310720);            //    32,768
    float*  wsqp = (float*) (ws + 1343488);            //     1,024
    float*  lacc = (float*) (ws + 1344512);            //         4
    int*    done = (int*)   (ws + 1344516);            //         4
    int*    wdone= (int*)   (ws + 1344520);            //         4

    hipMemsetAsync(ws + 1344512, 0, 12, stream);       // lacc, done, wdone

    hipLaunchKernelGGL(k_vq, dim3(256), dim3(1024), 0, stream,
                       z, pw, pb, ew, W4, wsq, wsqp, out, lacc, done, wdone);
}

// Round 6
// 153.944 us; speedup vs baseline: 1.0910x; 1.0910x over previous
//
#include <hip/hip_runtime.h>

// Problem constants
#define NPIX   32768      // B*H*W
#define NEMB_  8192
#define EMB_   64
#define CH_    128
#define CAPP   768        // LDS pair-queue capacity

// d_out layout (float elements)
#define OUT_OFF  0
#define ZQ_OFF   2097152
#define LOSS_OFF 4194304
#define IND_OFF  4194305

typedef _Float16 h8   __attribute__((ext_vector_type(8)));
typedef float    f16f __attribute__((ext_vector_type(16)));

// ---------------------------------------------------------------------------
// K1: codebook W-fragment pack + wsq + per-block max + pw transpose + init.
// grid 128 x 64 threads (one wave per block, 64 codes each).
__global__ __launch_bounds__(64) void k_wpack(
    const float* __restrict__ ew, const float* __restrict__ pw,
    float4* __restrict__ W4, float* __restrict__ pwT,
    float* __restrict__ wsq, float* __restrict__ wsqp,
    float* __restrict__ lacc, int* __restrict__ done)
{
    const int tid = threadIdx.x;
    // pw transpose: 8192 elements over 128 blocks
    {
        const int i = blockIdx.x * 64 + tid;
        const float v = pw[i];
        const int e = i >> 7, c = i & 127;
        pwT[c * 64 + e] = v;
    }
    const int m = blockIdx.x * 64 + tid;
    const float4* wr = (const float4*)(ew + (size_t)m * EMB_);
    float w[EMB_];
    float s = 0.f;
    #pragma unroll
    for (int i = 0; i < 16; i++) {
        float4 v = wr[i];
        w[4*i] = v.x; w[4*i+1] = v.y; w[4*i+2] = v.z; w[4*i+3] = v.w;
        s += v.x*v.x + v.y*v.y + v.z*v.z + v.w*v.w;
    }
    wsq[m] = s;
    float sh = (float)(_Float16)s;
    float sl = s - sh;
    const int t  = m >> 5;
    const int li = m & 31;
    #pragma unroll
    for (int s5 = 0; s5 < 4; s5++) {
        #pragma unroll
        for (int h = 0; h < 2; h++) {
            h8 hh;
            #pragma unroll
            for (int j = 0; j < 8; j++) hh[j] = (_Float16)w[s5 * 16 + h * 8 + j];
            W4[(size_t)(t * 5 + s5) * 64 + h * 32 + li] = __builtin_bit_cast(float4, hh);
        }
    }
    {
        h8 hh;
        #pragma unroll
        for (int j = 0; j < 8; j++) hh[j] = (_Float16)0.f;
        hh[0] = (_Float16)sh; hh[1] = (_Float16)sl;
        W4[(size_t)(t * 5 + 4) * 64 + 0 * 32 + li] = __builtin_bit_cast(float4, hh);
        #pragma unroll
        for (int j = 0; j < 8; j++) hh[j] = (_Float16)0.f;
        W4[(size_t)(t * 5 + 4) * 64 + 1 * 32 + li] = __builtin_bit_cast(float4, hh);
    }
    // single-wave max reduction
    float sm = s;
    #pragma unroll
    for (int o = 32; o > 0; o >>= 1) sm = fmaxf(sm, __shfl_xor(sm, o));
    if (tid == 0) wsqp[blockIdx.x] = sm;
    if (blockIdx.x == 0 && tid == 0) { *lacc = 0.f; *done = 0; }
}

// ---------------------------------------------------------------------------
// ordered-float key: lexicographic (dist, index) min == np argmin semantics
__device__ __forceinline__ unsigned long long pack_key(float d, int m)
{
    unsigned fb = __float_as_uint(d);
    fb ^= ((int)fb < 0) ? 0xFFFFFFFFu : 0x80000000u;
    return ((unsigned long long)fb << 32) | (unsigned)m;
}

// ---------------------------------------------------------------------------
// K2 fused: 128 px/block, 1024 threads (16 waves, 4 waves/SIMD, grid 256).
// Scan: wave wv = (chunk wv&7 of 32 tiles) x (px-group wv>>3 of 64 px).
// Trackers are per HALF-WAVE (16 of a tile's 32 codes each); the two sorted
// top-3 lists are merged ONCE after the tile loop (10 shfls instead of 64
// in-loop shfls). Merge is conservative: merged-cs3 >= true second-distinct-
// tile score, so the certify/push filter never misses a candidate tile.
__global__ __launch_bounds__(1024, 4) void k_fused3(
    const float4* __restrict__ W4, const float* __restrict__ z,
    const float* __restrict__ pwT, const float* __restrict__ pb,
    const float* __restrict__ wsqp, const float* __restrict__ wsq,
    const float* __restrict__ ew,
    float* __restrict__ out, float* __restrict__ lacc, int* __restrict__ done)
{
    __shared__ __align__(16) float xs[128][68];        // z_e rows, later winners
    __shared__ float s1s[1024], s2s[1024], s3s[1024];  // [px][ch], ch=0..7
    __shared__ short i1s[1024], i2s[1024];
    __shared__ float xsqp_s[8][128];
    __shared__ float thr_s[128];
    __shared__ int   pairs[CAPP];
    __shared__ unsigned long long pbest[128];
    __shared__ int   winner_s[128];
    __shared__ int   smask[128];
    __shared__ float wred[16];
    __shared__ int   npair_s;
    __shared__ float wm_s;

    const int tid  = threadIdx.x;
    const int wv   = tid >> 6;                       // 0..15
    const int lane = tid & 63;
    const int n0   = blockIdx.x * 128;
    const int hlf  = lane >> 5;

    if (tid == 0) npair_s = 0;
    if (tid < 128) { smask[tid] = 0; pbest[tid] = ~0ULL; }
    if (tid < 64) {
        float w = fmaxf(wsqp[tid], wsqp[tid + 64]);
        #pragma unroll
        for (int o = 32; o > 0; o >>= 1) w = fmaxf(w, __shfl_xor(w, o));
        if (tid == 0) wm_s = w;
    }

    // ---- fused projection: oct = tid>>7 (wave-uniform), px = tid&127 ----
    {
        const int oct = tid >> 7;
        const int pxp = tid & 127;
        const int e0  = __builtin_amdgcn_readfirstlane(oct << 3);  // SGPR
        const float* zp = z + (size_t)(n0 >> 10) * (CH_ * 1024) + (n0 & 1023) + pxp;
        float acc[8];
        #pragma unroll
        for (int j = 0; j < 8; j++) acc[j] = 0.f;
        #pragma unroll 8
        for (int c = 0; c < CH_; c++) {
            const float zv = zp[(size_t)c * 1024];               // coalesced
            const float4* wr = (const float4*)(pwT + c * 64 + e0);  // s_load
            float4 w0 = wr[0], w1 = wr[1];
            acc[0] = fmaf(zv, w0.x, acc[0]); acc[1] = fmaf(zv, w0.y, acc[1]);
            acc[2] = fmaf(zv, w0.z, acc[2]); acc[3] = fmaf(zv, w0.w, acc[3]);
            acc[4] = fmaf(zv, w1.x, acc[4]); acc[5] = fmaf(zv, w1.y, acc[5]);
            acc[6] = fmaf(zv, w1.z, acc[6]); acc[7] = fmaf(zv, w1.w, acc[7]);
        }
        const float4* pb4 = (const float4*)(pb + e0);
        float4 b0 = pb4[0], b1 = pb4[1];
        acc[0] += b0.x; acc[1] += b0.y; acc[2] += b0.z; acc[3] += b0.w;
        acc[4] += b1.x; acc[5] += b1.y; acc[6] += b1.z; acc[7] += b1.w;
        float sq = 0.f;
        #pragma unroll
        for (int j = 0; j < 8; j++) sq += acc[j] * acc[j];
        ((float4*)&xs[pxp][0])[oct * 2]     = make_float4(acc[0], acc[1], acc[2], acc[3]);
        ((float4*)&xs[pxp][0])[oct * 2 + 1] = make_float4(acc[4], acc[5], acc[6], acc[7]);
        xsqp_s[oct][pxp] = sq;
    }
    __syncthreads();

    const int ch = wv & 7;                 // chunk: tiles ch*32 .. ch*32+31
    const int pg = wv >> 3;                // px-group: px pg*64 .. pg*64+63

    // ---- B-fragments from LDS (2 px-tiles x 4 K-steps + shared tail) ----
    h8 bfr[2][4];
    #pragma unroll
    for (int j = 0; j < 2; j++) {
        const int px = pg * 64 + j * 32 + (lane & 31);
        #pragma unroll
        for (int s5 = 0; s5 < 4; s5++) {
            float4 u0 = *(const float4*)(&xs[px][s5 * 16 + hlf * 8]);
            float4 u1 = *(const float4*)(&xs[px][s5 * 16 + hlf * 8 + 4]);
            h8 hh;
            hh[0]=(_Float16)u0.x; hh[1]=(_Float16)u0.y; hh[2]=(_Float16)u0.z; hh[3]=(_Float16)u0.w;
            hh[4]=(_Float16)u1.x; hh[5]=(_Float16)u1.y; hh[6]=(_Float16)u1.z; hh[7]=(_Float16)u1.w;
            bfr[j][s5] = hh;
        }
    }
    h8 btail;                              // px-independent tail fragment
    {
        h8 hh;
        #pragma unroll
        for (int q = 0; q < 8; q++) hh[q] = (_Float16)0.f;
        if (hlf == 0) { hh[0] = (_Float16)-0.5f; hh[1] = (_Float16)-0.5f; }
        btail = hh;
    }

    // ---- coarse MFMA scan (per-half trackers, no in-loop shfl) ----
    const f16f kzero = {0,0,0,0,0,0,0,0,0,0,0,0,0,0,0,0};
    float s1[2], s2[2], s3[2];
    int   i1[2], i2[2];
    #pragma unroll
    for (int j = 0; j < 2; j++) { s1[j]=s2[j]=s3[j]=-3.0e38f; i1[j]=i2[j]=0; }

    const int tb = ch * 32;
    const float4* Wb = W4 + (size_t)tb * 320 + lane;
    float4 A[5];
    #pragma unroll
    for (int s = 0; s < 5; s++) A[s] = Wb[s * 64];

#define REDUCE_J(ACC, JJ, GT)                                                  \
    {                                                                          \
        float t0 = fmaxf(fmaxf(ACC[0],  ACC[1]),  ACC[2]);                     \
        float t1 = fmaxf(fmaxf(ACC[3],  ACC[4]),  ACC[5]);                     \
        float t2 = fmaxf(fmaxf(ACC[6],  ACC[7]),  ACC[8]);                     \
        float t3 = fmaxf(fmaxf(ACC[9],  ACC[10]), ACC[11]);                    \
        float t4 = fmaxf(fmaxf(ACC[12], ACC[13]), ACC[14]);                    \
        float v  = fmaxf(fmaxf(fmaxf(t0, t1), fmaxf(t2, t3)),                  \
                         fmaxf(t4, ACC[15]));                                  \
        bool c1 = v > s1[JJ];                                                  \
        bool c2 = v > s2[JJ];                                                  \
        int  cand = c1 ? i1[JJ] : (GT);                                        \
        i2[JJ] = c2 ? cand : i2[JJ];                                           \
        s3[JJ] = fmaxf(fminf(s2[JJ], v), s3[JJ]);                              \
        s3[JJ] = fminf(s3[JJ], fmaxf(s2[JJ], v));                              \
        s2[JJ] = fmaxf(fminf(s1[JJ], v), fminf(s2[JJ], fmaxf(s1[JJ], v)));     \
        i1[JJ] = c1 ? (GT) : i1[JJ];                                           \
        s1[JJ] = fmaxf(s1[JJ], v);                                             \
    }

    for (int tt = 0; tt < 32; tt++) {
        const int gt = tb + tt;
        // j = 0 chain (single 16-reg accumulator)
        f16f acc0 = __builtin_amdgcn_mfma_f32_32x32x16_f16(
            __builtin_bit_cast(h8, A[0]), bfr[0][0], kzero, 0, 0, 0);
        #pragma unroll
        for (int s = 1; s < 4; s++)
            acc0 = __builtin_amdgcn_mfma_f32_32x32x16_f16(
                __builtin_bit_cast(h8, A[s]), bfr[0][s], acc0, 0, 0, 0);
        acc0 = __builtin_amdgcn_mfma_f32_32x32x16_f16(
            __builtin_bit_cast(h8, A[4]), btail, acc0, 0, 0, 0);
        REDUCE_J(acc0, 0, gt)
        // j = 1 chain
        f16f acc1 = __builtin_amdgcn_mfma_f32_32x32x16_f16(
            __builtin_bit_cast(h8, A[0]), bfr[1][0], kzero, 0, 0, 0);
        #pragma unroll
        for (int s = 1; s < 4; s++)
            acc1 = __builtin_amdgcn_mfma_f32_32x32x16_f16(
                __builtin_bit_cast(h8, A[s]), bfr[1][s], acc1, 0, 0, 0);
        acc1 = __builtin_amdgcn_mfma_f32_32x32x16_f16(
            __builtin_bit_cast(h8, A[4]), btail, acc1, 0, 0, 0);
        // in-place A prefetch for tt+1 (A regs dead after the MFMAs above)
        {
            const int tp = (tt + 1) < 32 ? (tt + 1) : 31;
            const float4* wp = Wb + (size_t)tp * 320;
            #pragma unroll
            for (int s = 0; s < 5; s++) A[s] = wp[s * 64];
        }
        REDUCE_J(acc1, 1, gt)
    }
#undef REDUCE_J

    // ---- merge the two half-wave sorted-3 lists (once per wave) ----
    #pragma unroll
    for (int j = 0; j < 2; j++) {
        const float o1 = __shfl_xor(s1[j], 32);
        const float o2 = __shfl_xor(s2[j], 32);
        const float o3 = __shfl_xor(s3[j], 32);
        const int  oi1 = __shfl_xor(i1[j], 32);
        const int  oi2 = __shfl_xor(i2[j], 32);
        const bool a1  = s1[j] >= o1;
        const float m1 = a1 ? s1[j] : o1;
        const int  mi1 = a1 ? i1[j] : oi1;
        const float hA = a1 ? s2[j] : s1[j];
        const int  hAi = a1 ? i2[j] : i1[j];
        const float hB = a1 ? o1 : o2;
        const int  hBi = a1 ? oi1 : oi2;
        const bool b2  = hA >= hB;
        const float m2 = b2 ? hA : hB;
        const int  mi2 = b2 ? hAi : hBi;
        const float nA = b2 ? (a1 ? s3[j] : s2[j]) : hA;
        const float nB = b2 ? hB : (a1 ? o2 : o3);
        const float m3 = fmaxf(nA, nB);
        s1[j] = m1; s2[j] = m2; s3[j] = m3; i1[j] = mi1; i2[j] = mi2;
    }

    if (lane < 32) {
        #pragma unroll
        for (int j = 0; j < 2; j++) {
            const int px = pg * 64 + j * 32 + lane;
            const int cell = px * 8 + ch;
            s1s[cell] = s1[j]; s2s[cell] = s2[j]; s3s[cell] = s3[j];
            i1s[cell] = (short)i1[j]; i2s[cell] = (short)i2[j];
        }
    }
    __syncthreads();

    // ---- certify ----
    if (tid < 128) {
        float s1g = s1s[tid * 8];
        #pragma unroll
        for (int c = 1; c < 8; c++) s1g = fmaxf(s1g, s1s[tid * 8 + c]);
        float xq = xsqp_s[0][tid];
        #pragma unroll
        for (int o = 1; o < 8; o++) xq += xsqp_s[o][tid];
        float E = 0.00125f * sqrtf(xq * wm_s) + 1e-5f * wm_s + 3e-4f;
        thr_s[tid] = s1g - 2.0f * E;
    }
    __syncthreads();
    // ---- push candidate (px, tile) pairs (global tile ids 0..255) ----
    {
        const int cell = tid;                        // 128 px x 8 ch
        const int px = cell >> 3, chh = cell & 7;
        const float th = thr_s[px];
        const float cs1 = s1s[cell], cs2 = s2s[cell], cs3 = s3s[cell];
        if (cs3 >= th) {
            int pos = atomicAdd(&npair_s, 32);
            if (pos + 32 <= CAPP) {
                for (int t = 0; t < 32; t++)
                    pairs[pos + t] = (px << 8) | (chh * 32 + t);
            } else {
                for (int t = 0; t < 32; t++)
                    if (pos + t < CAPP) pairs[pos + t] = -1;
                smask[px] = 1;
            }
        } else {
            if (cs1 >= th) {
                int pos = atomicAdd(&npair_s, 1);
                if (pos < CAPP) pairs[pos] = (px << 8) | (int)i1s[cell];
                else smask[px] = 1;
            }
            if (cs2 >= th) {
                int pos = atomicAdd(&npair_s, 1);
                if (pos < CAPP) pairs[pos] = (px << 8) | (int)i2s[cell];
                else smask[px] = 1;
            }
        }
    }
    __syncthreads();
    const int np = npair_s < CAPP ? npair_s : CAPP;

    // ---- coalesced drain: one tile per wave-iter; 8 x 1KB contiguous ----
    const int lg = lane >> 4;
    const int ld = lane & 15;
    for (int i = wv; i < np; i += 16) {
        const int pr = pairs[i];
        if (pr < 0) continue;
        const int p = pr >> 8;
        if (smask[p]) continue;
        const int t = pr & 255;
        const float4* tb4 = (const float4*)(ew + (size_t)t * 2048);
        float4 wq[8];
        #pragma unroll
        for (int q = 0; q < 8; q++) wq[q] = tb4[q * 64 + lane];
        const float4 xq = *(const float4*)(&xs[p][ld * 4]);
        unsigned long long best = ~0ULL;
        #pragma unroll
        for (int q = 0; q < 8; q++) {
            float dp = wq[q].x*xq.x + wq[q].y*xq.y + wq[q].z*xq.z + wq[q].w*xq.w;
            dp += __shfl_xor(dp, 1);
            dp += __shfl_xor(dp, 2);
            dp += __shfl_xor(dp, 4);
            dp += __shfl_xor(dp, 8);
            const int m = t * 32 + q * 4 + lg;
            unsigned long long key = pack_key(fmaf(-2.f, dp, wsq[m]), m);
            best = key < best ? key : best;
        }
        { unsigned long long o = __shfl_xor(best, 16); best = o < best ? o : best; }
        { unsigned long long o = __shfl_xor(best, 32); best = o < best ? o : best; }
        if (lane == 0) atomicMin(&pbest[p], best);
    }
    // ---- overflow fallback: full codebook rescan (statistically never) ----
    for (int p = wv; p < 128; p += 16) {
        if (!smask[p]) continue;
        const float4 xq = *(const float4*)(&xs[p][ld * 4]);
        unsigned long long bk = ~0ULL;
        for (int t = 0; t < 256; t++) {
            const float4* tb4 = (const float4*)(ew + (size_t)t * 2048);
            #pragma unroll
            for (int q = 0; q < 8; q++) {
                float4 wv4 = tb4[q * 64 + lane];
                float dp = wv4.x*xq.x + wv4.y*xq.y + wv4.z*xq.z + wv4.w*xq.w;
                dp += __shfl_xor(dp, 1);
                dp += __shfl_xor(dp, 2);
                dp += __shfl_xor(dp, 4);
                dp += __shfl_xor(dp, 8);
                const int m = t * 32 + q * 4 + lg;
                unsigned long long key = pack_key(fmaf(-2.f, dp, wsq[m]), m);
                bk = key < bk ? key : bk;
            }
        }
        { unsigned long long o = __shfl_xor(bk, 16); bk = o < bk ? o : bk; }
        { unsigned long long o = __shfl_xor(bk, 32); bk = o < bk ? o : bk; }
        if (lane == 0) atomicMin(&pbest[p], bk);
    }
    __syncthreads();
    if (tid < 128) {
        const int win = (int)(unsigned)(pbest[tid] & 0xFFFFFFFFULL);
        winner_s[tid] = win;
        out[IND_OFF + n0 + tid] = (float)win;
    }
    __syncthreads();
    // ---- gather winner rows (8 thr/px), z_q writes, loss partials ----
    float lsum = 0.f;
    {
        const int px = tid >> 3, sg = tid & 7;
        const int win = winner_s[px];
        const float4* wr = (const float4*)(ew + (size_t)win * EMB_ + sg * 8);
        float4* xr  = (float4*)(&xs[px][sg * 8]);
        float4* zq4 = (float4*)(out + ZQ_OFF + (size_t)(n0 + px) * EMB_ + sg * 8);
        #pragma unroll
        for (int i = 0; i < 2; i++) {
            float4 w4v = wr[i];
            float4 z4  = xr[i];
            float d0 = w4v.x - z4.x, d1 = w4v.y - z4.y;
            float d2 = w4v.z - z4.z, d3 = w4v.w - z4.w;
            lsum += d0*d0 + d1*d1 + d2*d2 + d3*d3;
            xr[i]  = w4v;
            zq4[i] = w4v;
        }
    }
    __syncthreads();
    // ---- transposed out writes (64e x 128px, 512-B runs) ----
    {
        const int bI  = n0 >> 10;
        const int hw0 = n0 & 1023;
        float* ob = out + OUT_OFF + (size_t)bI * (EMB_ * 1024) + hw0;
        #pragma unroll
        for (int r = 0; r < 8; r++) {
            const int idx = r * 1024 + tid;
            const int e = idx >> 7, px = idx & 127;
            ob[(size_t)e * 1024 + px] = xs[px][e];
        }
    }
    // ---- loss reduction + final scalar ----
    {
        float v = lsum;
        #pragma unroll
        for (int o = 1; o < 64; o <<= 1) v += __shfl_xor(v, o);
        if (lane == 0) wred[wv] = v;
    }
    __syncthreads();
    if (tid == 0) {
        float s = wred[0];
        #pragma unroll
        for (int k = 1; k < 16; k++) s += wred[k];
        atomicAdd(lacc, s);
        __threadfence();
        int old = atomicAdd(done, 1);
        if (old == (int)gridDim.x - 1) {
            float tot = atomicAdd(lacc, 0.0f);
            out[LOSS_OFF] = 12.5f * (tot / 2097152.0f);
        }
    }
}

// ---------------------------------------------------------------------------
extern "C" void kernel_launch(void* const* d_in, const int* in_sizes, int n_in,
                              void* d_out, int out_size, void* d_ws, size_t ws_size,
                              hipStream_t stream)
{
    const float* z  = (const float*)d_in[0];
    const float* pw = (const float*)d_in[1];
    const float* pb = (const float*)d_in[2];
    const float* ew = (const float*)d_in[3];
    float* out = (float*)d_out;

    char* ws = (char*)d_ws;
    float4* W4   = (float4*)(ws);                      // 1,310,720
    float*  pwT  = (float*) (ws + 1310720);            //    32,768
    float*  wsq  = (float*) (ws + 1343488);            //    32,768
    float*  wsqp = (float*) (ws + 1376256);            //       512
    float*  lacc = (float*) (ws + 1376768);            //         4
    int*    done = (int*)   (ws + 1376772);            //         4

    hipLaunchKernelGGL(k_wpack,  dim3(128), dim3(64), 0, stream,
                       ew, pw, W4, pwT, wsq, wsqp, lacc, done);
    hipLaunchKernelGGL(k_fused3, dim3(256), dim3(1024), 0, stream,
                       W4, z, pwT, pb, wsqp, wsq, ew, out, lacc, done);
}